// Round 1
// baseline (147.322 us; speedup 1.0000x reference)
//
#include <hip/hip_runtime.h>
#include <limits.h>

#define NUSERS 1024
#define DDIM   128
#define MARGIN 0.2f
#define EPSV   1e-6f

struct Ws {
    int   firstIdx[NUSERS];
    int   secondIdx[NUSERS];
    int   cnt[NUSERS];
    int   diffIdx;      // first index j with uid[j] != uid[0]
    int   validCount;
    float total;
};

__global__ void k_init(Ws* ws) {
    int i = blockIdx.x * blockDim.x + threadIdx.x;
    if (i < NUSERS) {
        ws->firstIdx[i]  = INT_MAX;
        ws->secondIdx[i] = INT_MAX;
        ws->cnt[i]       = 0;
    }
    if (i == 0) {
        ws->diffIdx    = INT_MAX;
        ws->validCount = 0;
        ws->total      = 0.0f;
    }
}

__global__ void k_pass1(const int* __restrict__ uid, Ws* __restrict__ ws, int B) {
    int i = blockIdx.x * blockDim.x + threadIdx.x;
    if (i >= B) return;
    int u = uid[i];
    atomicMin(&ws->firstIdx[u], i);
    atomicAdd(&ws->cnt[u], 1);
    if (u != uid[0]) atomicMin(&ws->diffIdx, i);
}

__global__ void k_pass2(const int* __restrict__ uid, Ws* __restrict__ ws, int B) {
    int i = blockIdx.x * blockDim.x + threadIdx.x;
    if (i >= B) return;
    int u = uid[i];
    if (i != ws->firstIdx[u]) atomicMin(&ws->secondIdx[u], i);
}

// One 64-lane wave per sample. Each lane loads a float2 (2 consecutive floats)
// of the sample row, pos row, neg row => coalesced 512B per row per wave.
__global__ __launch_bounds__(256) void k_main(const float* __restrict__ proto,
                                              const int* __restrict__ uid,
                                              Ws* __restrict__ ws, int B) {
    const int gtid  = blockIdx.x * blockDim.x + threadIdx.x;
    const int wave  = gtid >> 6;          // sample index
    const int lane  = threadIdx.x & 63;
    const int wslot = threadIdx.x >> 6;   // wave slot within block (0..3)

    __shared__ float s_part[4];
    __shared__ int   s_valid[4];

    float contrib = 0.0f;
    int   validf  = 0;

    if (wave < B) {
        const int i  = wave;
        const int u  = uid[i];
        const int u0 = uid[0];
        const int c  = ws->cnt[u];
        const int f  = ws->firstIdx[u];
        const int g  = ws->diffIdx;

        const bool has_pos = (c >= 2);
        const bool has_neg = (u != u0) || (g != INT_MAX);

        if (has_pos && has_neg) {
            const int pos_idx = (f != i) ? f : ws->secondIdx[u];
            const int neg_idx = (u == u0) ? g : 0;

            const float2* a = (const float2*)(proto + (size_t)i       * DDIM);
            const float2* p = (const float2*)(proto + (size_t)pos_idx * DDIM);
            const float2* n = (const float2*)(proto + (size_t)neg_idx * DDIM);

            const float2 av = a[lane];
            const float2 pv = p[lane];
            const float2 nv = n[lane];

            const float dp0 = av.x - pv.x + EPSV;
            const float dp1 = av.y - pv.y + EPSV;
            const float dn0 = av.x - nv.x + EPSV;
            const float dn1 = av.y - nv.y + EPSV;

            float sp = dp0 * dp0 + dp1 * dp1;
            float sn = dn0 * dn0 + dn1 * dn1;

            #pragma unroll
            for (int off = 32; off > 0; off >>= 1) {
                sp += __shfl_down(sp, off);
                sn += __shfl_down(sn, off);
            }

            if (lane == 0) {
                const float per = sqrtf(sp) - sqrtf(sn) + MARGIN;
                contrib = per > 0.0f ? per : 0.0f;
                validf  = 1;
            }
        }
    }

    if (lane == 0) {
        s_part[wslot]  = contrib;
        s_valid[wslot] = validf;
    }
    __syncthreads();
    if (threadIdx.x == 0) {
        float t = s_part[0] + s_part[1] + s_part[2] + s_part[3];
        int   v = s_valid[0] + s_valid[1] + s_valid[2] + s_valid[3];
        if (t != 0.0f) atomicAdd(&ws->total, t);
        if (v != 0)    atomicAdd(&ws->validCount, v);
    }
}

__global__ void k_final(const Ws* __restrict__ ws, float* __restrict__ out) {
    int c = ws->validCount;
    if (c < 1) c = 1;
    out[0] = ws->total / (float)c;
}

extern "C" void kernel_launch(void* const* d_in, const int* in_sizes, int n_in,
                              void* d_out, int out_size, void* d_ws, size_t ws_size,
                              hipStream_t stream) {
    const float* proto = (const float*)d_in[0];
    const int*   uid   = (const int*)d_in[1];
    float*       out   = (float*)d_out;
    Ws*          ws    = (Ws*)d_ws;

    const int B = in_sizes[1];  // 16384

    k_init<<<(NUSERS + 255) / 256, 256, 0, stream>>>(ws);
    k_pass1<<<(B + 255) / 256, 256, 0, stream>>>(uid, ws, B);
    k_pass2<<<(B + 255) / 256, 256, 0, stream>>>(uid, ws, B);

    const int mainThreads = B * 64;
    k_main<<<(mainThreads + 255) / 256, 256, 0, stream>>>(proto, uid, ws, B);

    k_final<<<1, 1, 0, stream>>>(ws, out);
}

// Round 2
// 75.210 us; speedup vs baseline: 1.9588x; 1.9588x over previous
//
#include <hip/hip_runtime.h>
#include <limits.h>

#define NUSERS 1024
#define DDIM   128
#define MARGIN 0.2f
#define EPSV   1e-6f
#define NBLK   1024
#define NTHR   256

struct Ws {
    int   firstIdx[NUSERS];
    int   secondIdx[NUSERS];
    int   cnt[NUSERS];
    int   diffIdx;                // first index j with uid[j] != uid[0]
    float partialSum[NBLK];
    int   partialCnt[NBLK];
};

__global__ void k_init(Ws* ws) {
    int i = blockIdx.x * blockDim.x + threadIdx.x;
    if (i < NUSERS) {
        ws->firstIdx[i]  = INT_MAX;
        ws->secondIdx[i] = INT_MAX;
        ws->cnt[i]       = 0;
    }
    if (i == 0) ws->diffIdx = INT_MAX;
}

__global__ void k_meta1(const int* __restrict__ uid, Ws* __restrict__ ws, int B) {
    int i = blockIdx.x * blockDim.x + threadIdx.x;
    int u0 = uid[0];
    int cand = INT_MAX;
    if (i < B) {
        int u = uid[i];
        atomicMin(&ws->firstIdx[u], i);
        atomicAdd(&ws->cnt[u], 1);
        if (u != u0) cand = i;
    }
    // wave-level min to cut same-address atomic contention 64x
    #pragma unroll
    for (int off = 32; off > 0; off >>= 1) {
        int o = __shfl_down(cand, off);
        cand = (o < cand) ? o : cand;
    }
    if ((threadIdx.x & 63) == 0 && cand != INT_MAX)
        atomicMin(&ws->diffIdx, cand);
}

__global__ void k_meta2(const int* __restrict__ uid, Ws* __restrict__ ws, int B) {
    int i = blockIdx.x * blockDim.x + threadIdx.x;
    if (i >= B) return;
    int u = uid[i];
    if (i != ws->firstIdx[u]) atomicMin(&ws->secondIdx[u], i);
}

// Half-wave (32 lanes) per sample, float4 loads (32*16B = 512B = one row).
// Grid-stride over samples; per-block partials, no global atomics.
__global__ __launch_bounds__(NTHR) void k_main(const float* __restrict__ proto,
                                               const int* __restrict__ uid,
                                               Ws* __restrict__ ws, int B) {
    const int tid    = blockIdx.x * NTHR + threadIdx.x;
    const int halfId = tid >> 5;                    // global half-wave id
    const int nHalf  = (NBLK * NTHR) >> 5;          // total half-waves
    const int hl     = threadIdx.x & 31;            // lane within half-wave

    const int u0 = uid[0];
    const int g  = ws->diffIdx;

    float sum  = 0.0f;
    int   cntv = 0;

    for (int s = halfId; s < B; s += nHalf) {
        const int u = uid[s];
        const int c = ws->cnt[u];
        const int f = ws->firstIdx[u];

        const bool has_pos = (c >= 2);
        const bool has_neg = (u != u0) || (g != INT_MAX);

        if (has_pos && has_neg) {
            const int pos_idx = (f != s) ? f : ws->secondIdx[u];
            const int neg_idx = (u == u0) ? g : 0;

            const float4 av = ((const float4*)(proto + (size_t)s       * DDIM))[hl];
            const float4 pv = ((const float4*)(proto + (size_t)pos_idx * DDIM))[hl];
            const float4 nv = ((const float4*)(proto + (size_t)neg_idx * DDIM))[hl];

            const float dp0 = av.x - pv.x + EPSV;
            const float dp1 = av.y - pv.y + EPSV;
            const float dp2 = av.z - pv.z + EPSV;
            const float dp3 = av.w - pv.w + EPSV;
            const float dn0 = av.x - nv.x + EPSV;
            const float dn1 = av.y - nv.y + EPSV;
            const float dn2 = av.z - nv.z + EPSV;
            const float dn3 = av.w - nv.w + EPSV;

            float sp = dp0*dp0 + dp1*dp1 + dp2*dp2 + dp3*dp3;
            float sn = dn0*dn0 + dn1*dn1 + dn2*dn2 + dn3*dn3;

            // reduce within the 32-lane half (xor offsets <=16 stay in-half)
            #pragma unroll
            for (int off = 16; off > 0; off >>= 1) {
                sp += __shfl_xor(sp, off);
                sn += __shfl_xor(sn, off);
            }

            if (hl == 0) {
                const float per = sqrtf(sp) - sqrtf(sn) + MARGIN;
                sum += (per > 0.0f) ? per : 0.0f;
                cntv += 1;
            }
        }
    }

    // block reduction: one lane0 per half-wave -> LDS -> thread 0
    __shared__ float sF[NTHR / 32];
    __shared__ int   sC[NTHR / 32];
    if (hl == 0) {
        sF[threadIdx.x >> 5] = sum;
        sC[threadIdx.x >> 5] = cntv;
    }
    __syncthreads();
    if (threadIdx.x == 0) {
        float t = 0.0f; int v = 0;
        #pragma unroll
        for (int k = 0; k < NTHR / 32; ++k) { t += sF[k]; v += sC[k]; }
        ws->partialSum[blockIdx.x] = t;
        ws->partialCnt[blockIdx.x] = v;
    }
}

__global__ __launch_bounds__(256) void k_final(const Ws* __restrict__ ws,
                                               float* __restrict__ out) {
    float t = 0.0f; int c = 0;
    for (int i = threadIdx.x; i < NBLK; i += 256) {
        t += ws->partialSum[i];
        c += ws->partialCnt[i];
    }
    #pragma unroll
    for (int off = 32; off > 0; off >>= 1) {
        t += __shfl_down(t, off);
        c += __shfl_down(c, off);
    }
    __shared__ float sF[4];
    __shared__ int   sC[4];
    const int w = threadIdx.x >> 6;
    if ((threadIdx.x & 63) == 0) { sF[w] = t; sC[w] = c; }
    __syncthreads();
    if (threadIdx.x == 0) {
        float tt = sF[0] + sF[1] + sF[2] + sF[3];
        int   cc = sC[0] + sC[1] + sC[2] + sC[3];
        if (cc < 1) cc = 1;
        out[0] = tt / (float)cc;
    }
}

extern "C" void kernel_launch(void* const* d_in, const int* in_sizes, int n_in,
                              void* d_out, int out_size, void* d_ws, size_t ws_size,
                              hipStream_t stream) {
    const float* proto = (const float*)d_in[0];
    const int*   uid   = (const int*)d_in[1];
    float*       out   = (float*)d_out;
    Ws*          ws    = (Ws*)d_ws;

    const int B = in_sizes[1];  // 16384

    k_init <<<(NUSERS + 255) / 256, 256, 0, stream>>>(ws);
    k_meta1<<<(B + 255) / 256, 256, 0, stream>>>(uid, ws, B);
    k_meta2<<<(B + 255) / 256, 256, 0, stream>>>(uid, ws, B);
    k_main <<<NBLK, NTHR, 0, stream>>>(proto, uid, ws, B);
    k_final<<<1, 256, 0, stream>>>(ws, out);
}